// Round 8
// baseline (211.999 us; speedup 1.0000x reference)
//
#include <hip/hip_runtime.h>
#include <hip/hip_bf16.h>
#include <math.h>

typedef __bf16 bf16;
typedef __bf16 bf16x8 __attribute__((ext_vector_type(8)));
typedef float f32x4 __attribute__((ext_vector_type(4)));

#define SEQ 2048
#define EMB 1024
#define NH  16
#define HD  64
#define NROWS 4096   // B*S

// async global->LDS, 16B per lane (wave-uniform LDS base + lane*16)
#define GLOAD_LDS16(gp, lp)                                             \
    __builtin_amdgcn_global_load_lds(                                   \
        (const __attribute__((address_space(1))) void*)(gp),            \
        (__attribute__((address_space(3))) void*)(lp), 16, 0, 0)

// ---------------------------------------------------------------------------
// Kernel -1: fp32 -> bf16 conversion of all inputs into workspace.
// ---------------------------------------------------------------------------
__global__ __launch_bounds__(256) void cvt_kernel(
    const float* __restrict__ x,  const float* __restrict__ Wq,
    const float* __restrict__ Wk, const float* __restrict__ Wv,
    const float* __restrict__ Wo,
    bf16* __restrict__ xb, bf16* __restrict__ Wqb, bf16* __restrict__ Wkb,
    bf16* __restrict__ Wvb, bf16* __restrict__ Wob)
{
    int b = blockIdx.x;
    const float* src; bf16* dst; int boff;
    if      (b < 2048) { src = x;  dst = xb;  boff = b;        }
    else if (b < 2560) { src = Wq; dst = Wqb; boff = b - 2048; }
    else if (b < 3072) { src = Wk; dst = Wkb; boff = b - 2560; }
    else if (b < 3584) { src = Wv; dst = Wvb; boff = b - 3072; }
    else               { src = Wo; dst = Wob; boff = b - 3584; }
    size_t off = (size_t)boff * 2048 + (size_t)threadIdx.x * 8;
    float4 f0 = *(const float4*)(src + off);
    float4 f1 = *(const float4*)(src + off + 4);
    bf16x8 v;
    v[0] = (bf16)f0.x; v[1] = (bf16)f0.y; v[2] = (bf16)f0.z; v[3] = (bf16)f0.w;
    v[4] = (bf16)f1.x; v[5] = (bf16)f1.y; v[6] = (bf16)f1.z; v[7] = (bf16)f1.w;
    *(bf16x8*)(dst + off) = v;
}

// ---------------------------------------------------------------------------
// Kernel 0: RoPE cos/sin table  [S, 32] each, fp32 (computed in fp64)
// ---------------------------------------------------------------------------
__global__ void rope_table_kernel(float* __restrict__ ctab, float* __restrict__ stab) {
    int t = blockIdx.x * blockDim.x + threadIdx.x;   // 0 .. 65535
    int s = t >> 5;
    int j = t & 31;
    double freq = pow(10000.0, -(double)j / 32.0);
    double ang = (double)s * freq;
    ctab[t] = (float)cos(ang);
    stab[t] = (float)sin(ang);
}

// ---------------------------------------------------------------------------
// Kernel 1: fused QKV projection (y = x @ W^T) + RoPE epilogue.
//  m97-style: 128x128x32 tile, LDS staging via global_load_lds width=16.
//  Q pre-scaled by 1/32, stored [B,H,S,D].
//  K and V stored in MFMA-FRAGMENT ORDER so the attention kernel's fragment
//  loads are single coalesced global_load_dwordx4 (base + lane*16):
//   K: idx = ((bh*128 + key/16)*2 + d/32)*512 + ((d>>3)&3)*128 + (key&15)*8 + (d&7)
//   V: idx = ((bh*64 + key/32)*4 + (d>>4))*512 + ((key>>3)&3)*128 + (d&15)*8 + (key&7)
// ---------------------------------------------------------------------------
__global__ __launch_bounds__(256) void qkv_rope_kernel(
    const bf16* __restrict__ x,
    const bf16* __restrict__ Wq, const bf16* __restrict__ Wk, const bf16* __restrict__ Wv,
    const float* __restrict__ ctab, const float* __restrict__ stab,
    bf16* __restrict__ q_ws, bf16* __restrict__ kf_ws, bf16* __restrict__ vf_ws)
{
    __shared__ __align__(16) bf16 As[128 * 32];
    __shared__ __align__(16) bf16 Bs[128 * 32];

    const int t    = threadIdx.x;
    const int lane = t & 63;
    const int wave = t >> 6;
    const int col  = lane & 15;
    const int quad = lane >> 4;

    const int nblk = blockIdx.x;              // 0..23
    const int m0   = blockIdx.y * 128;

    const bf16* W; int nloc;
    if (nblk < 8)       { W = Wq; nloc = nblk * 128; }
    else if (nblk < 16) { W = Wk; nloc = (nblk - 8) * 128; }
    else                { W = Wv; nloc = (nblk - 16) * 128; }

    // staging chunk addresses: chunk c covers row c>>2, col-chunk (c&3)*8
    const bf16 *ga[2], *gb[2];
#pragma unroll
    for (int j = 0; j < 2; j++) {
        int c = t + j * 256;
        ga[j] = x + (size_t)(m0 + (c >> 2)) * EMB + (c & 3) * 8;
        gb[j] = W + (size_t)(nloc + (c >> 2)) * EMB + (c & 3) * 8;
    }

    const int wm = (wave >> 1) * 64;
    const int wn = (wave & 1) * 64;

    f32x4 acc[4][4];
#pragma unroll
    for (int i = 0; i < 4; i++)
#pragma unroll
        for (int j = 0; j < 4; j++) acc[i][j] = (f32x4){0.f, 0.f, 0.f, 0.f};

    for (int kc = 0; kc < EMB; kc += 32) {
#pragma unroll
        for (int j = 0; j < 2; j++) {
            int c = t + j * 256;
            GLOAD_LDS16(ga[j] + kc, As + c * 8);
            GLOAD_LDS16(gb[j] + kc, Bs + c * 8);
        }
        __syncthreads();
        bf16x8 a[4], b[4];
#pragma unroll
        for (int mt = 0; mt < 4; mt++)
            a[mt] = *(const bf16x8*)(As + (wm + mt * 16 + col) * 32 + quad * 8);
#pragma unroll
        for (int nt = 0; nt < 4; nt++)
            b[nt] = *(const bf16x8*)(Bs + (wn + nt * 16 + col) * 32 + quad * 8);
#pragma unroll
        for (int mt = 0; mt < 4; mt++)
#pragma unroll
            for (int nt = 0; nt < 4; nt++)
                acc[mt][nt] = __builtin_amdgcn_mfma_f32_16x16x32_bf16(a[mt], b[nt], acc[mt][nt], 0, 0, 0);
        __syncthreads();
    }

    // Epilogue: RoPE for Q,K (n < 2048); K,V to fragment-order layouts.
    const int n0w = nblk * 128 + wn;
    const int m0w = m0 + wm;
#pragma unroll
    for (int mt = 0; mt < 4; mt++) {
#pragma unroll
        for (int nt = 0; nt < 4; nt++) {
            int n  = n0w + nt * 16 + col;
            int d  = n & 63;
            int h  = (n >> 6) & 15;
            int jj = d >> 1;
#pragma unroll
            for (int r = 0; r < 4; r++) {
                int m  = m0w + mt * 16 + quad * 4 + r;
                int bb_ = m >> 11;
                int ss = m & (SEQ - 1);
                int bh = bb_ * NH + h;
                float v = acc[mt][nt][r];
                if (n < 2048) {   // uniform per block
                    float partner = __shfl_xor(v, 1, 64);
                    float c  = ctab[ss * 32 + jj];
                    float sn = stab[ss * 32 + jj];
                    float o = ((d & 1) == 0) ? (v * c - partner * sn)
                                             : (partner * sn + v * c);
                    if (n < 1024) {
                        q_ws[((size_t)bh * SEQ + ss) * HD + d] = (bf16)(o * 0.03125f);
                    } else {
                        size_t idx = ((size_t)(bh * 128 + (ss >> 4)) * 2 + (d >> 5)) * 512
                                   + ((d >> 3) & 3) * 128 + (ss & 15) * 8 + (d & 7);
                        kf_ws[idx] = (bf16)o;
                    }
                } else {
                    size_t idx = ((size_t)(bh * 64 + (ss >> 5)) * 4 + ((d >> 4) & 3)) * 512
                               + ((ss >> 3) & 3) * 128 + (d & 15) * 8 + (ss & 7);
                    vf_ws[idx] = (bf16)v;
                }
            }
        }
    }
}

// ---------------------------------------------------------------------------
// Kernel 2: flash attention (causal). Q pre-scaled by 1/32 upstream.
//  Fixed-reference softmax (m=0): split-K partials combine by pure addition.
//  R8: K/V read directly from global in MFMA-fragment order — every fragment
//  load is one coalesced global_load_dwordx4 (base + lane*16, 8 full lines).
//  No LDS staging, no per-step barriers, no bank conflicts (R7's bottleneck).
//  Block = 128 thr (2 waves) on one (32-row q-tile, head); waves take
//  interleaved 32-key tiles (wave0: s=0,2,..; wave1: s=1,3,..), combine via
//  LDS once at the end. K prefetched one step ahead (R5 pattern); V issued
//  at step top, consumed ~200cy later. Longest q-tiles dispatch first.
// ---------------------------------------------------------------------------
__global__ __launch_bounds__(128) void attn_kernel(
    const bf16* __restrict__ q_ws, const bf16* __restrict__ kf,
    const bf16* __restrict__ vf, bf16* __restrict__ attn_ws)
{
    __shared__ float comb_o[2][4][4][64];   // [frag][nt][r][lane] from wave1
    __shared__ float comb_l[2][64];

    const int lane = threadIdx.x & 63;
    const int wave = threadIdx.x >> 6;
    const int col  = lane & 15;
    const int quad = lane >> 4;

    const int qt = 63 - (int)(blockIdx.x >> 5);  // longest first, 64 q-tiles of 32
    const int bh = blockIdx.x & 31;              // b*16+h
    const int b_ = bh >> 4;
    const int h  = bh & 15;
    const int qb = qt * 32;
    const int nk = qt + 1;                       // 32-key tiles incl. diagonal

    const bf16* Q  = q_ws + (size_t)bh * SEQ * HD;
    const bf16* Kf = kf + (size_t)bh * 131072;   // 128 kb * 2 hf * 512
    const bf16* Vf = vf + (size_t)bh * 131072;   // 64 ks * 4 nt * 512

    // Q fragments (B-operand of S^T mfma): two 16-row frags (shared by waves)
    bf16x8 aq[2][2];
#pragma unroll
    for (int f = 0; f < 2; f++) {
        const bf16* qp = Q + (size_t)(qb + f * 16 + col) * HD + quad * 8;
        aq[f][0] = *(const bf16x8*)(qp);
        aq[f][1] = *(const bf16x8*)(qp + 32);
    }

    f32x4 acc_o[2][4];
#pragma unroll
    for (int f = 0; f < 2; f++)
#pragma unroll
        for (int i = 0; i < 4; i++) acc_o[f][i] = (f32x4){0.f, 0.f, 0.f, 0.f};
    float lsum[2] = {0.f, 0.f};

    // loop-invariant bpermute source addresses (byte addr = lane*4)
    int psrc[8];
#pragma unroll
    for (int j = 0; j < 8; j++)
        psrc[j] = ((((quad * 2 + (j >> 2)) & 3) << 4) | col) << 2;

    // ---- split-K interleaved loop
    int s0 = (wave < nk) ? wave : 0;
    bf16x8 Ka[2][2], nKa[2][2];
    {
        const bf16* p = Kf + (size_t)s0 * 2048 + lane * 8;
        Ka[0][0] = *(const bf16x8*)(p);
        Ka[0][1] = *(const bf16x8*)(p + 512);
        Ka[1][0] = *(const bf16x8*)(p + 1024);
        Ka[1][1] = *(const bf16x8*)(p + 1536);
    }

    for (int s = wave; s < nk; s += 2) {
        // ---- V fragments for this tile (consumed after softmax)
        bf16x8 Vb[4];
        {
            const bf16* p = Vf + (size_t)s * 2048 + lane * 8;
            Vb[0] = *(const bf16x8*)(p);
            Vb[1] = *(const bf16x8*)(p + 512);
            Vb[2] = *(const bf16x8*)(p + 1024);
            Vb[3] = *(const bf16x8*)(p + 1536);
        }

        // ---- S^T = K @ Q^T  (keys s*32 + g*16 + quad*4+r ; q = qb + f*16 + col)
        f32x4 sT[2][2];
#pragma unroll
        for (int g = 0; g < 2; g++)
#pragma unroll
            for (int f = 0; f < 2; f++) {
                f32x4 z = (f32x4){0.f, 0.f, 0.f, 0.f};
                z = __builtin_amdgcn_mfma_f32_16x16x32_bf16(Ka[g][0], aq[f][0], z, 0, 0, 0);
                z = __builtin_amdgcn_mfma_f32_16x16x32_bf16(Ka[g][1], aq[f][1], z, 0, 0, 0);
                sT[g][f] = z;
            }

        // ---- prefetch next K tile (clamped; K regs now free)
        {
            int sn = (s + 2 < nk) ? s + 2 : s;
            const bf16* p = Kf + (size_t)sn * 2048 + lane * 8;
            nKa[0][0] = *(const bf16x8*)(p);
            nKa[0][1] = *(const bf16x8*)(p + 512);
            nKa[1][0] = *(const bf16x8*)(p + 1024);
            nKa[1][1] = *(const bf16x8*)(p + 1536);
        }

        // ---- exp (+ causal mask on the diagonal tile only)
        float p[2][2][4];
        if (s == nk - 1) {
#pragma unroll
            for (int g = 0; g < 2; g++)
#pragma unroll
                for (int f = 0; f < 2; f++) {
                    const int qg = qb + f * 16 + col;
#pragma unroll
                    for (int r = 0; r < 4; r++) {
                        int key = s * 32 + g * 16 + quad * 4 + r;
                        float e = (key <= qg) ? __expf(sT[g][f][r]) : 0.f;
                        p[g][f][r] = e;
                        lsum[f] += e;
                    }
                }
        } else {
#pragma unroll
            for (int g = 0; g < 2; g++)
#pragma unroll
                for (int f = 0; f < 2; f++)
#pragma unroll
                    for (int r = 0; r < 4; r++) {
                        float e = __expf(sT[g][f][r]);
                        p[g][f][r] = e;
                        lsum[f] += e;
                    }
        }

        // ---- pack + bpermute to PV A-layout, then O += P @ V
#pragma unroll
        for (int f = 0; f < 2; f++) {
            unsigned int pk[4];
#pragma unroll
            for (int r = 0; r < 4; r++) {
                unsigned int lo = __builtin_bit_cast(unsigned short, (bf16)p[0][f][r]);
                unsigned int hi = __builtin_bit_cast(unsigned short, (bf16)p[1][f][r]);
                pk[r] = (hi << 16) | lo;
            }
            bf16x8 a_p;
#pragma unroll
            for (int j = 0; j < 8; j++) {
                unsigned int g = (unsigned int)__builtin_amdgcn_ds_bpermute(psrc[j], (int)pk[j & 3]);
                unsigned short bits = (quad < 2) ? (unsigned short)(g & 0xffff)
                                                 : (unsigned short)(g >> 16);
                a_p[j] = __builtin_bit_cast(bf16, bits);
            }
#pragma unroll
            for (int nt = 0; nt < 4; nt++)
                acc_o[f][nt] = __builtin_amdgcn_mfma_f32_16x16x32_bf16(a_p, Vb[nt], acc_o[f][nt], 0, 0, 0);
        }

        Ka[0][0] = nKa[0][0]; Ka[0][1] = nKa[0][1];
        Ka[1][0] = nKa[1][0]; Ka[1][1] = nKa[1][1];
    }

    // ---- wave1 publishes partials; wave0 merges (pure addition)
    if (wave == 1) {
#pragma unroll
        for (int f = 0; f < 2; f++) {
            comb_l[f][lane] = lsum[f];
#pragma unroll
            for (int nt = 0; nt < 4; nt++)
#pragma unroll
                for (int r = 0; r < 4; r++)
                    comb_o[f][nt][r][lane] = acc_o[f][nt][r];
        }
    }
    __syncthreads();

    if (wave == 0) {
#pragma unroll
        for (int f = 0; f < 2; f++) {
            lsum[f] += comb_l[f][lane];
#pragma unroll
            for (int nt = 0; nt < 4; nt++)
#pragma unroll
                for (int r = 0; r < 4; r++)
                    acc_o[f][nt][r] += comb_o[f][nt][r][lane];
        }

        // final l reduction across quads (q = col), normalize + store
#pragma unroll
        for (int f = 0; f < 2; f++) {
            lsum[f] += __shfl_xor(lsum[f], 16, 64);
            lsum[f] += __shfl_xor(lsum[f], 32, 64);
        }
#pragma unroll
        for (int f = 0; f < 2; f++)
#pragma unroll
            for (int r = 0; r < 4; r++) {
                float l_r = __shfl(lsum[f], quad * 4 + r, 64);
                float inv = 1.0f / l_r;
                int q = qb + f * 16 + quad * 4 + r;
                bf16* orow = attn_ws + (size_t)(b_ * SEQ + q) * EMB + h * HD;
#pragma unroll
                for (int nt = 0; nt < 4; nt++)
                    orow[nt * 16 + col] = (bf16)(acc_o[f][nt][r] * inv);
            }
    }
}

// ---------------------------------------------------------------------------
// Kernel 3: output projection  out = attn @ Wo^T   [4096,1024]x[1024,1024]
//  m97-style 128x64x32 tile (512 blocks -> 2/CU). Wave computes 64x32.
//  Output fp32 (reference dtype).
// ---------------------------------------------------------------------------
__global__ __launch_bounds__(256) void oproj_kernel(
    const bf16* __restrict__ attn_ws, const bf16* __restrict__ Wo,
    float* __restrict__ out)
{
    __shared__ __align__(16) bf16 As[128 * 32];
    __shared__ __align__(16) bf16 Bs[64 * 32];

    const int t    = threadIdx.x;
    const int lane = t & 63;
    const int wave = t >> 6;
    const int col  = lane & 15;
    const int quad = lane >> 4;

    const int n0 = blockIdx.x * 64;
    const int m0 = blockIdx.y * 128;

    const bf16 *ga[2], *gb;
#pragma unroll
    for (int j = 0; j < 2; j++) {
        int c = t + j * 256;
        ga[j] = attn_ws + (size_t)(m0 + (c >> 2)) * EMB + (c & 3) * 8;
    }
    gb = Wo + (size_t)(n0 + (t >> 2)) * EMB + (t & 3) * 8;

    const int wm = (wave >> 1) * 64;
    const int wn = (wave & 1) * 32;

    f32x4 acc[4][2];
#pragma unroll
    for (int i = 0; i < 4; i++)
#pragma unroll
        for (int j = 0; j < 2; j++) acc[i][j] = (f32x4){0.f, 0.f, 0.f, 0.f};

    for (int kc = 0; kc < EMB; kc += 32) {
#pragma unroll
        for (int j = 0; j < 2; j++) {
            int c = t + j * 256;
            GLOAD_LDS16(ga[j] + kc, As + c * 8);
        }
        GLOAD_LDS16(gb + kc, Bs + t * 8);
        __syncthreads();
        bf16x8 a[4], b[2];
#pragma unroll
        for (int mt = 0; mt < 4; mt++)
            a[mt] = *(const bf16x8*)(As + (wm + mt * 16 + col) * 32 + quad * 8);
#pragma unroll
        for (int nt = 0; nt < 2; nt++)
            b[nt] = *(const bf16x8*)(Bs + (wn + nt * 16 + col) * 32 + quad * 8);
#pragma unroll
        for (int mt = 0; mt < 4; mt++)
#pragma unroll
            for (int nt = 0; nt < 2; nt++)
                acc[mt][nt] = __builtin_amdgcn_mfma_f32_16x16x32_bf16(a[mt], b[nt], acc[mt][nt], 0, 0, 0);
        __syncthreads();
    }

#pragma unroll
    for (int mt = 0; mt < 4; mt++)
#pragma unroll
        for (int nt = 0; nt < 2; nt++)
#pragma unroll
            for (int r = 0; r < 4; r++) {
                int m = m0 + wm + mt * 16 + quad * 4 + r;
                int n = n0 + wn + nt * 16 + col;
                out[(size_t)m * EMB + n] = acc[mt][nt][r];
            }
}

// ---------------------------------------------------------------------------
// Workspace map (bytes):
//   [ 0, 8M)   q_ws   bf16 [B,H,S,D]  (pre-scaled by 1/32)
//   [ 8,16M)   kf_ws  bf16 fragment-order K
//   [16,24M)   vf_ws  bf16 fragment-order V
//   [24,32M)   xb     bf16 [B*S,E]     -- dead after qkv; reused as attn_ws
//   [32,34M)   Wqb    bf16 [E,E]
//   [34,36M)   Wkb
//   [36,38M)   Wvb
//   [38,40M)   Wob
//   [40,40.5M) ctab/stab fp32 [S,32] each
// ---------------------------------------------------------------------------
extern "C" void kernel_launch(void* const* d_in, const int* in_sizes, int n_in,
                              void* d_out, int out_size, void* d_ws, size_t ws_size,
                              hipStream_t stream) {
    const float* x  = (const float*)d_in[0];
    const float* Wq = (const float*)d_in[1];
    const float* Wk = (const float*)d_in[2];
    const float* Wv = (const float*)d_in[3];
    const float* Wo = (const float*)d_in[4];
    float* out = (float*)d_out;

    char* ws = (char*)d_ws;
    bf16* q_ws    = (bf16*)(ws);
    bf16* kf_ws   = (bf16*)(ws + (8u  << 20));
    bf16* vf_ws   = (bf16*)(ws + (16u << 20));
    bf16* xb      = (bf16*)(ws + (24u << 20));
    bf16* attn_ws = (bf16*)(ws + (24u << 20));   // aliases xb (dead by then)
    bf16* Wqb     = (bf16*)(ws + (32u << 20));
    bf16* Wkb     = (bf16*)(ws + (34u << 20));
    bf16* Wvb     = (bf16*)(ws + (36u << 20));
    bf16* Wob     = (bf16*)(ws + (38u << 20));
    float* ctab   = (float*)(ws + (40u << 20));
    float* stab   = ctab + SEQ * 32;

    hipLaunchKernelGGL(cvt_kernel, dim3(4096), dim3(256), 0, stream,
                       x, Wq, Wk, Wv, Wo, xb, Wqb, Wkb, Wvb, Wob);
    hipLaunchKernelGGL(rope_table_kernel, dim3(SEQ * 32 / 256), dim3(256), 0, stream,
                       ctab, stab);
    hipLaunchKernelGGL(qkv_rope_kernel, dim3(24, 32), dim3(256), 0, stream,
                       xb, Wqb, Wkb, Wvb, ctab, stab, q_ws, kf_ws, vf_ws);
    hipLaunchKernelGGL(attn_kernel, dim3(2048), dim3(128), 0, stream,
                       q_ws, kf_ws, vf_ws, attn_ws);
    hipLaunchKernelGGL(oproj_kernel, dim3(16, 32), dim3(256), 0, stream,
                       attn_ws, Wob, out);
}

// Round 9
// 180.657 us; speedup vs baseline: 1.1735x; 1.1735x over previous
//
#include <hip/hip_runtime.h>
#include <hip/hip_bf16.h>
#include <math.h>

typedef __bf16 bf16;
typedef __bf16 bf16x8 __attribute__((ext_vector_type(8)));
typedef float f32x4 __attribute__((ext_vector_type(4)));

#define SEQ 2048
#define EMB 1024
#define NH  16
#define HD  64
#define NROWS 4096   // B*S

// async global->LDS, 16B per lane (wave-uniform LDS base + lane*16)
#define GLOAD_LDS16(gp, lp)                                             \
    __builtin_amdgcn_global_load_lds(                                   \
        (const __attribute__((address_space(1))) void*)(gp),            \
        (__attribute__((address_space(3))) void*)(lp), 16, 0, 0)

// ---------------------------------------------------------------------------
// Kernel -1: fp32 -> bf16 conversion of all inputs + RoPE table (fused).
//  blocks 0..4095: convert; blocks 4096..4351: cos/sin table.
// ---------------------------------------------------------------------------
__global__ __launch_bounds__(256) void cvt_rope_kernel(
    const float* __restrict__ x,  const float* __restrict__ Wq,
    const float* __restrict__ Wk, const float* __restrict__ Wv,
    const float* __restrict__ Wo,
    bf16* __restrict__ xb, bf16* __restrict__ Wqb, bf16* __restrict__ Wkb,
    bf16* __restrict__ Wvb, bf16* __restrict__ Wob,
    float* __restrict__ ctab, float* __restrict__ stab)
{
    int b = blockIdx.x;
    if (b >= 4096) {
        int t = (b - 4096) * 256 + threadIdx.x;   // 0 .. 65535
        int s = t >> 5;
        int j = t & 31;
        double freq = pow(10000.0, -(double)j / 32.0);
        double ang = (double)s * freq;
        ctab[t] = (float)cos(ang);
        stab[t] = (float)sin(ang);
        return;
    }
    const float* src; bf16* dst; int boff;
    if      (b < 2048) { src = x;  dst = xb;  boff = b;        }
    else if (b < 2560) { src = Wq; dst = Wqb; boff = b - 2048; }
    else if (b < 3072) { src = Wk; dst = Wkb; boff = b - 2560; }
    else if (b < 3584) { src = Wv; dst = Wvb; boff = b - 3072; }
    else               { src = Wo; dst = Wob; boff = b - 3584; }
    size_t off = (size_t)boff * 2048 + (size_t)threadIdx.x * 8;
    float4 f0 = *(const float4*)(src + off);
    float4 f1 = *(const float4*)(src + off + 4);
    bf16x8 v;
    v[0] = (bf16)f0.x; v[1] = (bf16)f0.y; v[2] = (bf16)f0.z; v[3] = (bf16)f0.w;
    v[4] = (bf16)f1.x; v[5] = (bf16)f1.y; v[6] = (bf16)f1.z; v[7] = (bf16)f1.w;
    *(bf16x8*)(dst + off) = v;
}

// ---------------------------------------------------------------------------
// Kernel 1: fused QKV projection (y = x @ W^T) + RoPE epilogue.
//  m97-style GEMM (128x128x32, global_load_lds staging). R9: epilogue goes
//  through a per-wave LDS region (reusing the staging LDS after the final
//  barrier): scalar ds_writes into the target layout, then ds_read_b128 +
//  coalesced global_store_dwordx4 over fully contiguous 1KB runs — replaces
//  64 scattered scalar global stores/lane (R8's measured qkv regression).
//  Q pre-scaled by 1/32, stored [B,H,S,D]. K,V stored in MFMA-fragment order.
// ---------------------------------------------------------------------------
__global__ __launch_bounds__(256) void qkv_rope_kernel(
    const bf16* __restrict__ x,
    const bf16* __restrict__ Wq, const bf16* __restrict__ Wk, const bf16* __restrict__ Wv,
    const float* __restrict__ ctab, const float* __restrict__ stab,
    bf16* __restrict__ q_ws, bf16* __restrict__ kf_ws, bf16* __restrict__ vf_ws)
{
    __shared__ __align__(16) bf16 SMEM[18432];   // 36864 B
    bf16* As = SMEM;                 // 128*32
    bf16* Bs = SMEM + 4096;          // 128*32

    const int t    = threadIdx.x;
    const int lane = t & 63;
    const int wave = t >> 6;
    const int col  = lane & 15;
    const int quad = lane >> 4;

    const int nblk = blockIdx.x;              // 0..23
    const int m0   = blockIdx.y * 128;

    const bf16* W; int nloc;
    if (nblk < 8)       { W = Wq; nloc = nblk * 128; }
    else if (nblk < 16) { W = Wk; nloc = (nblk - 8) * 128; }
    else                { W = Wv; nloc = (nblk - 16) * 128; }

    const bf16 *ga[2], *gb[2];
#pragma unroll
    for (int j = 0; j < 2; j++) {
        int c = t + j * 256;
        ga[j] = x + (size_t)(m0 + (c >> 2)) * EMB + (c & 3) * 8;
        gb[j] = W + (size_t)(nloc + (c >> 2)) * EMB + (c & 3) * 8;
    }

    const int wm = (wave >> 1) * 64;
    const int wn = (wave & 1) * 64;

    f32x4 acc[4][4];
#pragma unroll
    for (int i = 0; i < 4; i++)
#pragma unroll
        for (int j = 0; j < 4; j++) acc[i][j] = (f32x4){0.f, 0.f, 0.f, 0.f};

    for (int kc = 0; kc < EMB; kc += 32) {
#pragma unroll
        for (int j = 0; j < 2; j++) {
            int c = t + j * 256;
            GLOAD_LDS16(ga[j] + kc, As + c * 8);
            GLOAD_LDS16(gb[j] + kc, Bs + c * 8);
        }
        __syncthreads();
        bf16x8 a[4], b[4];
#pragma unroll
        for (int mt = 0; mt < 4; mt++)
            a[mt] = *(const bf16x8*)(As + (wm + mt * 16 + col) * 32 + quad * 8);
#pragma unroll
        for (int nt = 0; nt < 4; nt++)
            b[nt] = *(const bf16x8*)(Bs + (wn + nt * 16 + col) * 32 + quad * 8);
#pragma unroll
        for (int mt = 0; mt < 4; mt++)
#pragma unroll
            for (int nt = 0; nt < 4; nt++)
                acc[mt][nt] = __builtin_amdgcn_mfma_f32_16x16x32_bf16(a[mt], b[nt], acc[mt][nt], 0, 0, 0);
        __syncthreads();   // after final iter: all LDS reads done -> safe to reuse
    }

    // ---- epilogue: RoPE + LDS transpose -> coalesced stores ----
    bf16* Es = SMEM + wave * 4608;               // 9216 B per wave (Q: 64x72)

    const int n0w  = nblk * 128 + wn;
    const int m0w  = m0 + wm;
    const int bb_  = m0w >> 11;
    const int ss0  = m0w & (SEQ - 1);
    const int h    = (n0w >> 6) & 15;
    const int bh   = bb_ * NH + h;
    const int kind = (n0w < 1024) ? 0 : (n0w < 2048 ? 1 : 2);  // Q/K/V

#pragma unroll
    for (int mt = 0; mt < 4; mt++) {
#pragma unroll
        for (int nt = 0; nt < 4; nt++) {
            const int d  = nt * 16 + col;
            const int jj = d >> 1;
#pragma unroll
            for (int r = 0; r < 4; r++) {
                const int ss_l = mt * 16 + quad * 4 + r;
                float v = acc[mt][nt][r];
                if (kind < 2) {   // uniform per block
                    float partner = __shfl_xor(v, 1, 64);
                    float c  = ctab[(ss0 + ss_l) * 32 + jj];
                    float sn = stab[(ss0 + ss_l) * 32 + jj];
                    float o = ((d & 1) == 0) ? (v * c - partner * sn)
                                             : (partner * sn + v * c);
                    if (kind == 0) {
                        Es[ss_l * 72 + d] = (bf16)(o * 0.03125f);   // pre-scaled Q
                    } else {
                        int eoff = ((ss_l >> 4) * 2 + (d >> 5)) * 512
                                 + ((d >> 3) & 3) * 128 + (ss_l & 15) * 8 + (d & 7);
                        Es[eoff] = (bf16)o;
                    }
                } else {
                    int eoff = ((ss_l >> 5) * 4 + (d >> 4)) * 512
                             + ((ss_l >> 3) & 3) * 128 + (d & 15) * 8 + (ss_l & 7);
                    Es[eoff] = (bf16)v;
                }
            }
        }
    }
    // wave-private region: no barrier needed; compiler inserts lgkmcnt waits.

    const int row = lane >> 3, c8 = lane & 7;
    if (kind == 0) {
        bf16* qbase = q_ws + ((size_t)bh * SEQ + ss0) * HD;
#pragma unroll
        for (int i = 0; i < 8; i++) {
            bf16x8 vv = *(const bf16x8*)&Es[(i * 8 + row) * 72 + c8 * 8];
            *(bf16x8*)(qbase + (size_t)(i * 8 + row) * HD + c8 * 8) = vv;
        }
    } else if (kind == 1) {
        bf16* kbase = kf_ws + ((size_t)bh * 128 + (ss0 >> 4)) * 1024;
#pragma unroll
        for (int i = 0; i < 8; i++) {
            bf16x8 vv = *(const bf16x8*)&Es[i * 512 + lane * 8];
            *(bf16x8*)(kbase + i * 512 + lane * 8) = vv;
        }
    } else {
        bf16* vbase = vf_ws + ((size_t)bh * 64 + (ss0 >> 5)) * 2048;
#pragma unroll
        for (int i = 0; i < 8; i++) {
            bf16x8 vv = *(const bf16x8*)&Es[i * 512 + lane * 8];
            *(bf16x8*)(vbase + i * 512 + lane * 8) = vv;
        }
    }
}

// ---------------------------------------------------------------------------
// Kernel 2: flash attention (causal). Q pre-scaled by 1/32 upstream.
//  Fixed-reference softmax (m=0): split-K partials combine by pure addition.
//  K/V read directly from global in MFMA-fragment order — every fragment
//  load is one coalesced global_load_dwordx4 (base + lane*16, 8 full lines).
//  Block = 128 thr (2 waves) on one (32-row q-tile, head); waves take
//  interleaved 32-key tiles, combine via LDS once at the end. K prefetched
//  one step ahead; V issued at step top. Longest q-tiles dispatch first.
// ---------------------------------------------------------------------------
__global__ __launch_bounds__(128) void attn_kernel(
    const bf16* __restrict__ q_ws, const bf16* __restrict__ kf,
    const bf16* __restrict__ vf, bf16* __restrict__ attn_ws)
{
    __shared__ float comb_o[2][4][4][64];   // [frag][nt][r][lane] from wave1
    __shared__ float comb_l[2][64];

    const int lane = threadIdx.x & 63;
    const int wave = threadIdx.x >> 6;
    const int col  = lane & 15;
    const int quad = lane >> 4;

    const int qt = 63 - (int)(blockIdx.x >> 5);  // longest first, 64 q-tiles of 32
    const int bh = blockIdx.x & 31;              // b*16+h
    const int b_ = bh >> 4;
    const int h  = bh & 15;
    const int qb = qt * 32;
    const int nk = qt + 1;                       // 32-key tiles incl. diagonal

    const bf16* Q  = q_ws + (size_t)bh * SEQ * HD;
    const bf16* Kf = kf + (size_t)bh * 131072;
    const bf16* Vf = vf + (size_t)bh * 131072;

    bf16x8 aq[2][2];
#pragma unroll
    for (int f = 0; f < 2; f++) {
        const bf16* qp = Q + (size_t)(qb + f * 16 + col) * HD + quad * 8;
        aq[f][0] = *(const bf16x8*)(qp);
        aq[f][1] = *(const bf16x8*)(qp + 32);
    }

    f32x4 acc_o[2][4];
#pragma unroll
    for (int f = 0; f < 2; f++)
#pragma unroll
        for (int i = 0; i < 4; i++) acc_o[f][i] = (f32x4){0.f, 0.f, 0.f, 0.f};
    float lsum[2] = {0.f, 0.f};

    int psrc[8];
#pragma unroll
    for (int j = 0; j < 8; j++)
        psrc[j] = ((((quad * 2 + (j >> 2)) & 3) << 4) | col) << 2;

    int s0 = (wave < nk) ? wave : 0;
    bf16x8 Ka[2][2], nKa[2][2];
    {
        const bf16* p = Kf + (size_t)s0 * 2048 + lane * 8;
        Ka[0][0] = *(const bf16x8*)(p);
        Ka[0][1] = *(const bf16x8*)(p + 512);
        Ka[1][0] = *(const bf16x8*)(p + 1024);
        Ka[1][1] = *(const bf16x8*)(p + 1536);
    }

    for (int s = wave; s < nk; s += 2) {
        bf16x8 Vb[4];
        {
            const bf16* p = Vf + (size_t)s * 2048 + lane * 8;
            Vb[0] = *(const bf16x8*)(p);
            Vb[1] = *(const bf16x8*)(p + 512);
            Vb[2] = *(const bf16x8*)(p + 1024);
            Vb[3] = *(const bf16x8*)(p + 1536);
        }

        f32x4 sT[2][2];
#pragma unroll
        for (int g = 0; g < 2; g++)
#pragma unroll
            for (int f = 0; f < 2; f++) {
                f32x4 z = (f32x4){0.f, 0.f, 0.f, 0.f};
                z = __builtin_amdgcn_mfma_f32_16x16x32_bf16(Ka[g][0], aq[f][0], z, 0, 0, 0);
                z = __builtin_amdgcn_mfma_f32_16x16x32_bf16(Ka[g][1], aq[f][1], z, 0, 0, 0);
                sT[g][f] = z;
            }

        {
            int sn = (s + 2 < nk) ? s + 2 : s;
            const bf16* p = Kf + (size_t)sn * 2048 + lane * 8;
            nKa[0][0] = *(const bf16x8*)(p);
            nKa[0][1] = *(const bf16x8*)(p + 512);
            nKa[1][0] = *(const bf16x8*)(p + 1024);
            nKa[1][1] = *(const bf16x8*)(p + 1536);
        }

        float p[2][2][4];
        if (s == nk - 1) {
#pragma unroll
            for (int g = 0; g < 2; g++)
#pragma unroll
                for (int f = 0; f < 2; f++) {
                    const int qg = qb + f * 16 + col;
#pragma unroll
                    for (int r = 0; r < 4; r++) {
                        int key = s * 32 + g * 16 + quad * 4 + r;
                        float e = (key <= qg) ? __expf(sT[g][f][r]) : 0.f;
                        p[g][f][r] = e;
                        lsum[f] += e;
                    }
                }
        } else {
#pragma unroll
            for (int g = 0; g < 2; g++)
#pragma unroll
                for (int f = 0; f < 2; f++)
#pragma unroll
                    for (int r = 0; r < 4; r++) {
                        float e = __expf(sT[g][f][r]);
                        p[g][f][r] = e;
                        lsum[f] += e;
                    }
        }

#pragma unroll
        for (int f = 0; f < 2; f++) {
            unsigned int pk[4];
#pragma unroll
            for (int r = 0; r < 4; r++) {
                unsigned int lo = __builtin_bit_cast(unsigned short, (bf16)p[0][f][r]);
                unsigned int hi = __builtin_bit_cast(unsigned short, (bf16)p[1][f][r]);
                pk[r] = (hi << 16) | lo;
            }
            bf16x8 a_p;
#pragma unroll
            for (int j = 0; j < 8; j++) {
                unsigned int g = (unsigned int)__builtin_amdgcn_ds_bpermute(psrc[j], (int)pk[j & 3]);
                unsigned short bits = (quad < 2) ? (unsigned short)(g & 0xffff)
                                                 : (unsigned short)(g >> 16);
                a_p[j] = __builtin_bit_cast(bf16, bits);
            }
#pragma unroll
            for (int nt = 0; nt < 4; nt++)
                acc_o[f][nt] = __builtin_amdgcn_mfma_f32_16x16x32_bf16(a_p, Vb[nt], acc_o[f][nt], 0, 0, 0);
        }

        Ka[0][0] = nKa[0][0]; Ka[0][1] = nKa[0][1];
        Ka[1][0] = nKa[1][0]; Ka[1][1] = nKa[1][1];
    }

    if (wave == 1) {
#pragma unroll
        for (int f = 0; f < 2; f++) {
            comb_l[f][lane] = lsum[f];
#pragma unroll
            for (int nt = 0; nt < 4; nt++)
#pragma unroll
                for (int r = 0; r < 4; r++)
                    comb_o[f][nt][r][lane] = acc_o[f][nt][r];
        }
    }
    __syncthreads();

    if (wave == 0) {
#pragma unroll
        for (int f = 0; f < 2; f++) {
            lsum[f] += comb_l[f][lane];
#pragma unroll
            for (int nt = 0; nt < 4; nt++)
#pragma unroll
                for (int r = 0; r < 4; r++)
                    acc_o[f][nt][r] += comb_o[f][nt][r][lane];
        }

#pragma unroll
        for (int f = 0; f < 2; f++) {
            lsum[f] += __shfl_xor(lsum[f], 16, 64);
            lsum[f] += __shfl_xor(lsum[f], 32, 64);
        }
#pragma unroll
        for (int f = 0; f < 2; f++)
#pragma unroll
            for (int r = 0; r < 4; r++) {
                float l_r = __shfl(lsum[f], quad * 4 + r, 64);
                float inv = 1.0f / l_r;
                int q = qb + f * 16 + quad * 4 + r;
                bf16* orow = attn_ws + (size_t)(b_ * SEQ + q) * EMB + h * HD;
#pragma unroll
                for (int nt = 0; nt < 4; nt++)
                    orow[nt * 16 + col] = (bf16)(acc_o[f][nt][r] * inv);
            }
    }
}

// ---------------------------------------------------------------------------
// Kernel 3: output projection  out = attn @ Wo^T   [4096,1024]x[1024,1024]
//  m97-style 128x64x32 tile. R9: LDS-transpose epilogue -> 8 coalesced
//  global_store_dwordx4 per lane (full 128B-line segments) instead of 32
//  scattered scalar dword stores.
// ---------------------------------------------------------------------------
__global__ __launch_bounds__(256) void oproj_kernel(
    const bf16* __restrict__ attn_ws, const bf16* __restrict__ Wo,
    float* __restrict__ out)
{
    __shared__ __align__(16) char SM[36864];
    bf16* As = (bf16*)SM;             // 128*32
    bf16* Bs = (bf16*)(SM + 8192);    // 64*32

    const int t    = threadIdx.x;
    const int lane = t & 63;
    const int wave = t >> 6;
    const int col  = lane & 15;
    const int quad = lane >> 4;

    const int n0 = blockIdx.x * 64;
    const int m0 = blockIdx.y * 128;

    const bf16 *ga[2], *gb;
#pragma unroll
    for (int j = 0; j < 2; j++) {
        int c = t + j * 256;
        ga[j] = attn_ws + (size_t)(m0 + (c >> 2)) * EMB + (c & 3) * 8;
    }
    gb = Wo + (size_t)(n0 + (t >> 2)) * EMB + (t & 3) * 8;

    const int wm = (wave >> 1) * 64;
    const int wn = (wave & 1) * 32;

    f32x4 acc[4][2];
#pragma unroll
    for (int i = 0; i < 4; i++)
#pragma unroll
        for (int j = 0; j < 2; j++) acc[i][j] = (f32x4){0.f, 0.f, 0.f, 0.f};

    for (int kc = 0; kc < EMB; kc += 32) {
#pragma unroll
        for (int j = 0; j < 2; j++) {
            int c = t + j * 256;
            GLOAD_LDS16(ga[j] + kc, As + c * 8);
        }
        GLOAD_LDS16(gb + kc, Bs + t * 8);
        __syncthreads();
        bf16x8 a[4], b[2];
#pragma unroll
        for (int mt = 0; mt < 4; mt++)
            a[mt] = *(const bf16x8*)(As + (wm + mt * 16 + col) * 32 + quad * 8);
#pragma unroll
        for (int nt = 0; nt < 2; nt++)
            b[nt] = *(const bf16x8*)(Bs + (wn + nt * 16 + col) * 32 + quad * 8);
#pragma unroll
        for (int mt = 0; mt < 4; mt++)
#pragma unroll
            for (int nt = 0; nt < 2; nt++)
                acc[mt][nt] = __builtin_amdgcn_mfma_f32_16x16x32_bf16(a[mt], b[nt], acc[mt][nt], 0, 0, 0);
        __syncthreads();   // final barrier -> LDS reusable
    }

    // ---- LDS-transpose epilogue: 64x32 fp32 per wave, row stride 36 ----
    float* Os = (float*)(SM + (size_t)wave * 9216);
#pragma unroll
    for (int mt = 0; mt < 4; mt++)
#pragma unroll
        for (int nt = 0; nt < 2; nt++)
#pragma unroll
            for (int r = 0; r < 4; r++)
                Os[(mt * 16 + quad * 4 + r) * 36 + nt * 16 + col] = acc[mt][nt][r];

    const int row = lane >> 3, c8 = lane & 7;
    float* obase = out + (size_t)(m0 + wm) * EMB + n0 + wn;
#pragma unroll
    for (int i = 0; i < 8; i++) {
        float4 vv = *(const float4*)&Os[(i * 8 + row) * 36 + c8 * 4];
        *(float4*)(obase + (size_t)(i * 8 + row) * EMB + c8 * 4) = vv;
    }
}

// ---------------------------------------------------------------------------
// Workspace map (bytes):
//   [ 0, 8M)   q_ws   bf16 [B,H,S,D]  (pre-scaled by 1/32)
//   [ 8,16M)   kf_ws  bf16 fragment-order K
//   [16,24M)   vf_ws  bf16 fragment-order V
//   [24,32M)   xb     bf16 [B*S,E]     -- dead after qkv; reused as attn_ws
//   [32,34M)   Wqb    bf16 [E,E]
//   [34,36M)   Wkb
//   [36,38M)   Wvb
//   [38,40M)   Wob
//   [40,40.5M) ctab/stab fp32 [S,32] each
// ---------------------------------------------------------------------------
extern "C" void kernel_launch(void* const* d_in, const int* in_sizes, int n_in,
                              void* d_out, int out_size, void* d_ws, size_t ws_size,
                              hipStream_t stream) {
    const float* x  = (const float*)d_in[0];
    const float* Wq = (const float*)d_in[1];
    const float* Wk = (const float*)d_in[2];
    const float* Wv = (const float*)d_in[3];
    const float* Wo = (const float*)d_in[4];
    float* out = (float*)d_out;

    char* ws = (char*)d_ws;
    bf16* q_ws    = (bf16*)(ws);
    bf16* kf_ws   = (bf16*)(ws + (8u  << 20));
    bf16* vf_ws   = (bf16*)(ws + (16u << 20));
    bf16* xb      = (bf16*)(ws + (24u << 20));
    bf16* attn_ws = (bf16*)(ws + (24u << 20));   // aliases xb (dead by then)
    bf16* Wqb     = (bf16*)(ws + (32u << 20));
    bf16* Wkb     = (bf16*)(ws + (34u << 20));
    bf16* Wvb     = (bf16*)(ws + (36u << 20));
    bf16* Wob     = (bf16*)(ws + (38u << 20));
    float* ctab   = (float*)(ws + (40u << 20));
    float* stab   = ctab + SEQ * 32;

    hipLaunchKernelGGL(cvt_rope_kernel, dim3(4352), dim3(256), 0, stream,
                       x, Wq, Wk, Wv, Wo, xb, Wqb, Wkb, Wvb, Wob, ctab, stab);
    hipLaunchKernelGGL(qkv_rope_kernel, dim3(24, 32), dim3(256), 0, stream,
                       xb, Wqb, Wkb, Wvb, ctab, stab, q_ws, kf_ws, vf_ws);
    hipLaunchKernelGGL(attn_kernel, dim3(2048), dim3(128), 0, stream,
                       q_ws, kf_ws, vf_ws, attn_ws);
    hipLaunchKernelGGL(oproj_kernel, dim3(16, 32), dim3(256), 0, stream,
                       attn_ws, Wob, out);
}